// Round 1
// baseline (71.459 us; speedup 1.0000x reference)
//
#include <hip/hip_runtime.h>
#include <math.h>

// Preisach hysteresis, N=256, parallel-in-time clamp-scan, 2 dispatches.
//
// Per row r the state is a staircase: +1 for j<=c_r, -1 for c_r<j<=r.
// Step update: c = max(min(c, k_t), r_t) with
//   up   (h>hp): k=256, r_t = (row < u_t ? row : -1), u_t = #{i : i*d < h}
//   down (h<hp): k = max{j : j*d <= h}, r_t = -1
// Clamps compose associatively: chunk == c -> max(min(c,HI),LO).
//   K1: per-chunk codes + per-row (LO,HI) + per-GROUP (LO,HI) via LDS;
//       packed G table build (global ws); out[t] pre-init to offset.
//   K3: 2 blocks per chunk (126 blocks x 128 thr), each block owns a
//       DISJOINT half of the packed G table (idx [0,259) = rows {0-63,
//       192-255}; idx [259,518) = rows {64-191}; 66304 B each):
//       async-DMA half to LDS overlapped with the entry-state scan;
//       32-step replay with 2 quad-perm DPP reduces + LDS partials
//       (replaces the 6-level butterfly chain); one 32-thread final
//       reduction; halves merged via atomicAdd (out pre-init in K1).
//
// Packed G column i holds rows {i, 255-i, 64+i, 191-i} = exactly 518 floats:
//   row i     : idx0 = 0        row 255-i : idx0 = i+2
//   row 64+i  : idx0 = 259      row 191-i : idx0 = 325+i
// addr = idx*64 + col.  G_r[e] = 2*P_r(e-1) - Tot_r, e in [0, r+1],
// P = prefix sums of softplus(raw row r).

#define CL 32               // chunk length (time steps per chunk)
#define HROWS 259           // packed-table rows per k3 half
#define HBYTES (HROWS * 64 * 4)   // 66304 B per half
#define AS1 __attribute__((address_space(1)))
#define AS3 __attribute__((address_space(3)))

__device__ __forceinline__ int make_code(const float* __restrict__ h, int t, int T) {
    const float delta = 1.0f / 255.0f;          // fl(1/255), matches jnp.linspace
    int code = 256;                              // no-op: k=256, u=0
    if (t < T) {
        const float hc = h[t];
        const float hp = (t == 0) ? 0.0f : h[t - 1];
        if (hc > hp) {
            // u-1 = max{ i : (float)i*delta < hc }   (yy >= h keeps state)
            int i2 = (int)(hc * 255.0f);
            if (i2 > 255) i2 = 255;
            while (i2 < 255 && (float)(i2 + 1) * delta < hc) ++i2;
            while (i2 >= 0 && (float)i2 * delta >= hc) --i2;
            code = ((i2 + 1) << 16) | 256;
        } else if (hc < hp) {
            // k = max{ j : (float)j*delta <= hc }    (xx <= h keeps state)
            int kk = (int)(hc * 255.0f);
            if (kk > 255) kk = 255;
            while (kk < 255 && (float)(kk + 1) * delta <= hc) ++kk;
            while (kk > 0 && (float)kk * delta > hc) --kk;
            code = kk;
        }
    }
    return code;
}

// ---- K1: blocks [0,NB1): codes + per-row chunk (LO,HI) + group (LO,HI)
//          blocks [NB1, NB1+64): G build (1 row per wave) + out[t]=offset
__global__ __launch_bounds__(256)
void k1_compose_gbuild(const float* __restrict__ h, const float* __restrict__ raw,
                       int* __restrict__ codes, int2* __restrict__ lohi,
                       int2* __restrict__ glohi, float* __restrict__ Gg,
                       float* __restrict__ out, const float* __restrict__ offset,
                       int T, int NCH, int NB1) {
    const int b = blockIdx.x;
    const int tid = threadIdx.x;
    const int w = tid >> 6, l = tid & 63;
    if (b < NB1) {
        __shared__ int2 slh[4][256];             // per-chunk clamps, 8 KB
        const int q = b * 4 + w;                 // chunk for this wave
        int mycode = 256;                        // no-op (q>=NCH -> identity)
        if (q < NCH && l < CL) {
            mycode = make_code(h, q * CL + l, T);
            codes[q * CL + l] = mycode;
        }
        // compose chunk clamp for rows r = 64*j + l (shfl-broadcast the codes)
        int lo[4] = {-1, -1, -1, -1}, hi[4] = {256, 256, 256, 256};
        #pragma unroll
        for (int s = 0; s < CL; ++s) {
            const int cd = __shfl(mycode, s);
            const int k = cd & 0xFFFF, u = cd >> 16;
            #pragma unroll
            for (int j = 0; j < 4; ++j) {
                const int r = j * 64 + l;
                const int rr = (r < u) ? r : -1;
                lo[j] = max(min(lo[j], k), rr);
                hi[j] = max(min(hi[j], k), rr);
            }
        }
        #pragma unroll
        for (int j = 0; j < 4; ++j) {
            slh[w][j * 64 + l] = make_int2(lo[j], hi[j]);
            if (q < NCH) lohi[q * 256 + j * 64 + l] = make_int2(lo[j], hi[j]);
        }
        __syncthreads();
        // group clamp: thread = row; compose the block's 4 chunks in order
        int glo = -1, ghi = 256;
        #pragma unroll
        for (int w2 = 0; w2 < 4; ++w2) {
            const int2 lh = slh[w2][tid];        // stride-2 banks: free
            glo = max(min(glo, lh.y), lh.x);
            ghi = max(min(ghi, lh.y), lh.x);
        }
        glohi[b * 256 + tid] = make_int2(glo, ghi);
    } else {
        // ---- out init: out[t] = offset (k3 halves atomicAdd onto this)
        for (int t = (b - NB1) * 256 + tid; t < T; t += 64 * 256)
            out[t] = offset[0];
        // ---- G build: wave (b-NB1)*4 + w builds row r
        const int r = (b - NB1) * 4 + w;
        const int tri = r * (r + 1) / 2;
        int lcol, idx0;
        if (r < 64)       { lcol = r;       idx0 = 0; }
        else if (r < 128) { lcol = r - 64;  idx0 = 259; }
        else if (r < 192) { lcol = 191 - r; idx0 = 325 + lcol; }
        else              { lcol = 255 - r; idx0 = lcol + 2; }

        float Pseg[4];
        float carry = 0.0f;
        const int nseg = r / 64 + 1;
        #pragma unroll
        for (int s = 0; s < 4; ++s) {
            Pseg[s] = 0.0f;
            if (s < nseg) {
                const int j = s * 64 + l;
                float v = 0.0f;
                if (j <= r) {
                    const float x = raw[tri + j];
                    // jax.nn.softplus(x) = max(x,0) + log1p(exp(-|x|))
                    v = fmaxf(x, 0.0f) + log1pf(expf(-fabsf(x)));
                }
                #pragma unroll
                for (int off = 1; off < 64; off <<= 1) {
                    const float t2 = __shfl_up(v, off);
                    if (l >= off) v += t2;
                }
                Pseg[s] = carry + v;             // inclusive prefix P_j
                carry += __shfl(v, 63);          // segment total
            }
        }
        const float tot = carry;
        if (l == 0) Gg[idx0 * 64 + lcol] = -tot;             // e=0: 2*P(-1)-Tot
        #pragma unroll
        for (int s = 0; s < 4; ++s) {
            const int j = s * 64 + l;
            if (j <= r) Gg[(idx0 + 1 + j) * 64 + lcol] = 2.0f * Pseg[s] - tot;
        }
    }
}

// ---- K3: 2 blocks per chunk, 128 thr (2 waves); DMA half-table || entry scan,
//          then replay with DPP quad-reduce + LDS partials; atomicAdd merge
__global__ __launch_bounds__(128)
void k3_eval(const int* __restrict__ codes, const int2* __restrict__ lohi,
             const int2* __restrict__ glohi, const float* __restrict__ Gg,
             const float* __restrict__ scale, float* __restrict__ out,
             int T, int NCH) {
    __shared__ __align__(16) float Gl[HROWS * 64]; // 66304 B (this block's half)
    __shared__ int cds[CL];
    __shared__ float pc[CL * 33];                  // 32 quad-partials/step, pad 33

    const int tid = threadIdx.x;
    const int w = tid >> 6, l = tid & 63;
    const int q = blockIdx.x >> 1;               // chunk
    const int half = blockIdx.x & 1;             // which table half / row band

    // this thread's row:
    //   half 0: wave0 -> rows 0..63,   wave1 -> rows 192..255
    //   half 1: wave0 -> rows 64..127, wave1 -> rows 128..191
    const int r = half ? (w ? 128 + l : 64 + l) : (w ? 192 + l : l);

    // chunk codes: issue early (in-order vmcnt, lands before DMA drain)
    if (tid < CL) cds[tid] = codes[q * CL + tid];

    // ---- async G staging: direct global->LDS DMA of THIS half only.
    // dest = wave-uniform LDS base + lane*16 (m104); flat layout matches.
    // 32 iters x 2 waves x 1024 B = 65536 B; 48-float4 remainder plain.
    {
        const char* gsrc = (const char*)Gg + (size_t)half * HBYTES;
        char* lbase = (char*)Gl;
        #pragma unroll 8
        for (int it = 0; it < 32; ++it) {
            const int off = it * 2048 + w * 1024;
            __builtin_amdgcn_global_load_lds(
                (const AS1 void*)(gsrc + off + l * 16),
                (AS3 void*)(lbase + off), 16, 0, 0);
        }
        if (tid < 48) {
            ((float4*)Gl)[4096 + tid] = ((const float4*)gsrc)[4096 + tid];
        }
    }

    // ---- entry state for row r: g group clamps + (q&3) chunk clamps
    // (bit-identical to composing all q chunk clamps left-to-right;
    //  rows are disjoint across the two half-blocks -> no duplicated loads)
    int c = -1;
    {
        const int g = q >> 2;
        #pragma unroll 8
        for (int j = 0; j < g; ++j) {
            const int2 lh = glohi[j * 256 + r];
            c = max(min(c, lh.y), lh.x);
        }
        #pragma unroll
        for (int j = g * 4; j < q; ++j) {
            const int2 lh = lohi[j * 256 + r];
            c = max(min(c, lh.y), lh.x);
        }
    }
    __syncthreads();                             // drains DMA (vmcnt) + cds

    // gather address within this half: Gl[(gbase + c)*64 + lcol]
    // (lane-private column -> 2-way bank alias only: free)
    //   half0 w0: row l     -> gbase 1      (idx0 0,   e idx 1+c)
    //   half0 w1: row 192+l -> gbase 66-l   (idx0 65-l)
    //   half1 w0: row 64+l  -> gbase 260-259 = 1
    //   half1 w1: row 128+l -> gbase 389-l-259 = 130-l
    int gbase, lcol;
    if (w == 0) { gbase = 1; lcol = l; }
    else        { gbase = (half ? 130 : 66) - l; lcol = 63 - l; }

    // replay: per-step gather + 2 quad-perm DPP reduces; lanes l%4==0 write
    // the quad partial to LDS. No 6-level butterfly -> serial chain is just
    // the cheap VALU c-update; gathers/writes pipeline on the LDS pipe.
    const int slot = (w << 4) | (l >> 2);        // 0..31 partials per step
    const bool wr = (l & 3) == 0;
    #pragma unroll
    for (int s = 0; s < CL; ++s) {
        const int cd = cds[s];                   // uniform -> LDS broadcast
        const int k = cd & 0xFFFF, u = cd >> 16;
        c = max(min(c, k), (r < u) ? r : -1);
        float p = Gl[(gbase + c) * 64 + lcol];
        p += __shfl_xor(p, 1);                   // quad_perm DPP (VALU)
        p += __shfl_xor(p, 2);
        if (wr) pc[s * 33 + slot] = p;           // pad 33: conflict-free
    }
    __syncthreads();

    // final: one thread per step sums 32 quad-partials (4-acc tree),
    // then merges this half into out via atomicAdd (out pre-init = offset)
    if (tid < CL) {
        const int t = q * CL + tid;
        if (t < T) {
            const float* row = &pc[tid * 33];    // banks (tid+i)%32: clean
            float a0 = 0.0f, a1 = 0.0f, a2 = 0.0f, a3 = 0.0f;
            #pragma unroll
            for (int i = 0; i < 32; i += 4) {
                a0 += row[i]; a1 += row[i + 1]; a2 += row[i + 2]; a3 += row[i + 3];
            }
            const float sum = (a0 + a1) + (a2 + a3);
            atomicAdd(&out[t], sum * (1.0f / 32896.0f) * scale[0]);
        }
    }
}

extern "C" void kernel_launch(void* const* d_in, const int* in_sizes, int n_in,
                              void* d_out, int out_size, void* d_ws, size_t ws_size,
                              hipStream_t stream) {
    const float* h      = (const float*)d_in[0];
    const float* raw    = (const float*)d_in[1];
    const float* offset = (const float*)d_in[2];
    const float* scale  = (const float*)d_in[3];
    float* out = (float*)d_out;
    const int T = in_sizes[0];
    const int NCH = (T + CL - 1) / CL;           // 63 chunks at T=2000
    const int NB1 = (NCH + 3) / 4;               // 4 chunks (waves) per k1 block

    // ws carve-up (16B-aligned)
    char* ws = (char*)d_ws;
    size_t o = 0;
    int* codes  = (int*)(ws + o);  o += ((size_t)NCH * CL * 4 + 15) & ~15ull;
    int2* lohi  = (int2*)(ws + o); o += (size_t)NCH * 256 * 8;
    int2* glohi = (int2*)(ws + o); o += (size_t)NB1 * 256 * 8;
    float* Gg   = (float*)(ws + o);              // 518*64*4 = 132608 B

    k1_compose_gbuild<<<NB1 + 64, 256, 0, stream>>>(h, raw, codes, lohi, glohi,
                                                    Gg, out, offset, T, NCH, NB1);
    k3_eval<<<2 * NCH, 128, 0, stream>>>(codes, lohi, glohi, Gg, scale,
                                         out, T, NCH);
}